// Round 15
// baseline (74.509 us; speedup 1.0000x reference)
//
#include <hip/hip_runtime.h>
#include <stdint.h>

#define NLOC 469
#define NCLS 80
#define NFLAT 37520
#define TOPK 1000
#define NB 512           // compact hist: valid bin15 in [24230,24511] subset of [BOFF,BOFF+511]
#define BOFF 24192
#define CAP 2048         // candidate capacity (LDS)
#define ROWS_PB 250      // maskbuild rows per block (4 blocks)

typedef unsigned long long u64;

__device__ __forceinline__ float sigm(float x) { return 1.0f / (1.0f + expf(-x)); }

// order-preserving float -> uint32 (greater float => greater uint)
__device__ __forceinline__ uint32_t f2o(float f) {
    uint32_t u = __float_as_uint(f);
    return (u & 0x80000000u) ? ~u : (u | 0x80000000u);
}

// ------------------------------------------- K1: decode (parallel, 147 blocks)
__global__ void decode_kernel(
    const float* __restrict__ s0, const float* __restrict__ l0, const float* __restrict__ c0,
    const float* __restrict__ s1, const float* __restrict__ l1, const float* __restrict__ c1,
    const float* __restrict__ s2, const float* __restrict__ l2, const float* __restrict__ c2,
    u64* __restrict__ keys, float4* __restrict__ bbox, unsigned short* __restrict__ bin16)
{
    int t = blockIdx.x * blockDim.x + threadIdx.x;
    if (t < NFLAT) {
        int p = t / NCLS;
        int k = t - p * NCLS;
        int c = k + 1;                       // class channel (0 = background, dropped)
        const float* sr; const float* cr; int local, hw;
        if (p < 350)      { sr = s0; cr = c0; local = p;       hw = 350; }
        else if (p < 441) { sr = s1; cr = c1; local = p - 350; hw = 91;  }
        else              { sr = s2; cr = c2; local = p - 441; hw = 28;  }
        float val = sqrtf(sigm(sr[c * hw + local]) * sigm(cr[local]));
        bool valid = (val >= 0.05f);
        float masked = valid ? val : -1.0f;
        // key: value-major, tie -> lower index wins (larger low word)
        u64 key = ((u64)f2o(masked) << 32) | (u64)(0xFFFFFFFFu - (uint32_t)t);
        keys[t] = key;
        bin16[t] = valid ? (unsigned short)(key >> 49) : (unsigned short)0;
    }
    if (t < NLOC) {
        int p = t;
        const float* lr; int local, hw, w; float is;
        if (p < 350)      { lr = l0; local = p;       hw = 350; w = 25; is = 16.0f; }
        else if (p < 441) { lr = l1; local = p - 350; hw = 91;  w = 13; is = 32.0f; }
        else              { lr = l2; local = p - 441; hw = 28;  w = 7;  is = 64.0f; }
        int y = local / w, x = local - y * w;
        float px = ((float)x + 0.5f) * is;
        float py = ((float)y + 0.5f) * is;
        float L = lr[local] * is;
        float T = lr[hw + local] * is;
        float R = lr[2 * hw + local] * is;
        float B = lr[3 * hw + local] * is;
        bbox[p] = make_float4(px - L, py - T, px + R, py + B);
    }
}

// ---------------- K2: top-k select + exact rank (1 block, per-wave sub-hists)
__global__ void __launch_bounds__(1024, 4) topk_kernel(
    const u64* __restrict__ keys, const unsigned short* __restrict__ bin16,
    float* __restrict__ tvalG, int* __restrict__ tidxG)
{
    __shared__ int histW[16 * NB];   // 32 KB: per-wave sub-hists (kills same-addr serialization)
    __shared__ int histS[NB];
    __shared__ u64 candL[CAP];
    __shared__ int bstar_s;
    int tid = threadIdx.x;
    int wv = tid >> 6;

    // A0: register-batch prefetch of packed bins
    const uint32_t* b2 = (const uint32_t*)bin16;    // 2 bins per u32, NFLAT/2 = 18760
    const int nw = (tid < 328) ? 19 : 18;           // 18760 = 18*1024 + 328
    uint32_t vbuf[19];
    #pragma unroll
    for (int k = 0; k < 19; ++k) {
        int t = tid + (k << 10);
        if (t < NFLAT / 2) vbuf[k] = b2[t];
    }
    if (tid == 0) bstar_s = 0;
    for (int z = tid; z < 16 * NB; z += 1024) histW[z] = 0;
    __syncthreads();
    // A2: per-wave hist build from registers (valid-only; sentinel 0 skipped)
    int* myh = &histW[wv * NB];
    #pragma unroll
    for (int k = 0; k < 19; ++k) {
        if (k < nw) {
            uint32_t v = vbuf[k];
            int b0 = (int)(v & 0xffffu), b1 = (int)(v >> 16);
            if (b0) atomicAdd(&myh[b0 - BOFF], 1);
            if (b1) atomicAdd(&myh[b1 - BOFF], 1);
        }
    }
    __syncthreads();
    // A2b: reduce 16 sub-hists
    if (tid < NB) {
        int s = 0;
        #pragma unroll
        for (int w = 0; w < 16; ++w) s += histW[w * NB + tid];
        histS[tid] = s;
    }
    __syncthreads();
    // A3: single-wave select over 512 bins
    if (tid < 64) {
        int bs = NB - 8 * (tid + 1);                // lane 0 owns HIGHEST 8 bins
        int h[8];
        int s = 0;
        #pragma unroll
        for (int k = 0; k < 8; ++k) { h[k] = histS[bs + k]; s += h[k]; }
        int ws = s;
        #pragma unroll
        for (int d = 1; d < 64; d <<= 1) {
            int v = __shfl_up(ws, d, 64);
            if (tid >= d) ws += v;
        }
        int cumAbove = ws - s;
        if (cumAbove < TOPK && ws >= TOPK) {        // exactly one lane crosses
            int running = cumAbove;
            #pragma unroll
            for (int k = 7; k >= 0; --k) {
                if (running + h[k] >= TOPK) { bstar_s = BOFF + bs + k; break; }
                running += h[k];
            }
        }
        int run = cumAbove;                         // starts, descending bin-major
        #pragma unroll
        for (int k = 7; k >= 0; --k) { histS[bs + k] = run; run += h[k]; }
    }
    __syncthreads();
    int Bstar = bstar_s;
    // A4: counting-sort scatter (register reuse -> no second bin read)
    #pragma unroll
    for (int k = 0; k < 19; ++k) {
        if (k < nw) {
            uint32_t v = vbuf[k];
            int b0 = (int)(v & 0xffffu), b1 = (int)(v >> 16);
            int t2 = (tid + (k << 10)) * 2;
            if (b0 >= Bstar) {
                int pos = atomicAdd(&histS[b0 - BOFF], 1);
                if (pos < CAP) candL[pos] = keys[t2];
            }
            if (b1 >= Bstar) {
                int pos = atomicAdd(&histS[b1 - BOFF], 1);
                if (pos < CAP) candL[pos] = keys[t2 + 1];
            }
        }
    }
    __syncthreads();
    int C = min(histS[Bstar - BOFF], CAP);          // end(Bstar) == candidate count
    // A5: exact rank within bin segment -> global tval/tidx
    for (int p = tid; p < C; p += 1024) {
        u64 k = candL[p];
        int bidx = (int)(k >> 49) - BOFF;
        int segL = (bidx == NB - 1) ? 0 : min(histS[bidx + 1], CAP);
        int segR = min(histS[bidx], CAP);
        int cnt = segL;
        for (int q = segL; q < segR; ++q)
            cnt += (candL[q] > k) ? 1 : 0;
        if (cnt < TOPK) {
            uint32_t o = (uint32_t)(k >> 32);
            uint32_t u = (o & 0x80000000u) ? (o ^ 0x80000000u) : ~o;  // inverse f2o
            tvalG[cnt] = __uint_as_float(u);
            tidxG[cnt] = (int)(0xFFFFFFFFu - (uint32_t)(k & 0xFFFFFFFFu));
        }
    }
}

// ---------------- K3: row-parallel class-sparse mask build (4 blocks x 256)
__global__ void __launch_bounds__(256) maskbuild_kernel(
    const int* __restrict__ tidxG, const float4* __restrict__ bbox,
    uint32_t* __restrict__ maskG, unsigned char* __restrict__ zbyte)
{
    __shared__ float4 sboxL[TOPK];                  // 16000 B
    __shared__ uint32_t rowW[ROWS_PB * 32];         // 32000 B block-local mask rows
    __shared__ unsigned char lab8[TOPK];
    __shared__ unsigned short csorted[TOPK];
    __shared__ int clsStart[NCLS], clsCur[NCLS];
    __shared__ float redMax[4], redMin[4];
    __shared__ float Mp1_s;
    __shared__ int dmax_s;

    int tid = threadIdx.x;
    int lane = tid & 63, wv = tid >> 6;

    for (int z = tid; z < ROWS_PB * 32; z += 256) rowW[z] = 0u;
    // gather all 1000 boxes + labels; reduce max/min (fmax/fmin exact, order-free)
    float m = -3.0e38f, lmin = 3.0e38f;
    for (int j = tid; j < TOPK; j += 256) {
        int idx = tidxG[j];
        int p = idx / NCLS;
        int lab = idx - p * NCLS;
        float4 b = bbox[p];
        sboxL[j] = b; lab8[j] = (unsigned char)lab;
        m = fmaxf(m, fmaxf(fmaxf(b.x, b.y), fmaxf(b.z, b.w)));
        lmin = fminf(lmin, fminf(b.x, b.y));
    }
    for (int o = 32; o > 0; o >>= 1) {
        m = fmaxf(m, __shfl_down(m, o, 64));
        lmin = fminf(lmin, __shfl_down(lmin, o, 64));
    }
    if (lane == 0) { redMax[wv] = m; redMin[wv] = lmin; }
    if (tid < NCLS) clsCur[tid] = 0;
    __syncthreads();
    if (tid == 0) {
        float mm = redMax[0], ll = redMin[0];
        for (int q = 1; q < 4; ++q) { mm = fmaxf(mm, redMax[q]); ll = fminf(ll, redMin[q]); }
        float Mp1 = mm + 1.0f;
        Mp1_s = Mp1;
        int dm = 79;
        if (Mp1 > 0.0f) {
            float ratio = (mm - ll) / Mp1;
            dm = (int)ceilf(ratio);
            if (dm < 0) dm = 0;
            if (dm > 79) dm = 79;
        }
        dmax_s = dm;
    }
    __syncthreads();
    float Mp1 = Mp1_s;
    for (int j = tid; j < TOPK; j += 256) {
        float off = (float)lab8[j] * Mp1;
        float4 b = sboxL[j];
        sboxL[j] = make_float4(b.x + off, b.y + off, b.z + off, b.w + off);
        atomicAdd(&clsCur[lab8[j]], 1);
    }
    __syncthreads();
    // single-wave exclusive scan of 80 class counts
    if (tid < 64) {
        int l = tid;
        int e0 = clsCur[l];
        int e1 = (l < 16) ? clsCur[64 + l] : 0;
        int s = e0;
        #pragma unroll
        for (int d = 1; d < 64; d <<= 1) {
            int v = __shfl_up(s, d, 64);
            if (l >= d) s += v;
        }
        int tot64 = __shfl(s, 63, 64);
        int s2 = e1;
        #pragma unroll
        for (int d = 1; d < 16; d <<= 1) {
            int v = __shfl_up(s2, d, 64);
            if (l >= d) s2 += v;
        }
        int ex0 = s - e0;
        clsStart[l] = ex0;
        clsCur[l] = ex0;
        if (l < 16) {
            int ex1 = tot64 + s2 - e1;
            clsStart[64 + l] = ex1;
            clsCur[64 + l] = ex1;
        }
    }
    __syncthreads();
    for (int j = tid; j < TOPK; j += 256) {
        int pos = atomicAdd(&clsCur[lab8[j]], 1);
        csorted[pos] = (unsigned short)j;
    }
    __syncthreads();                         // clsCur[c] is now END of class c
    // sparse pair IoU for this block's rows
    if (tid < ROWS_PB) {
        int i = blockIdx.x * ROWS_PB + tid;
        int c = lab8[i];
        float4 si = sboxL[i];
        float ai = fmaxf(si.z - si.x, 0.f) * fmaxf(si.w - si.y, 0.f);
        int dmax = dmax_s;
        int clo = c - dmax; if (clo < 0) clo = 0;
        int chi = c + dmax; if (chi > NCLS - 1) chi = NCLS - 1;
        bool nz = false;
        for (int cc = clo; cc <= chi; ++cc) {
            int mE = clsCur[cc];
            for (int mm2 = clsStart[cc]; mm2 < mE; ++mm2) {
                int j = csorted[mm2];
                if (j > i) {
                    float4 sj = sboxL[j];
                    float aj = fmaxf(sj.z - sj.x, 0.f) * fmaxf(sj.w - sj.y, 0.f);
                    float ltx = fmaxf(si.x, sj.x), lty = fmaxf(si.y, sj.y);
                    float rbx = fminf(si.z, sj.z), rby = fminf(si.w, sj.w);
                    float iw = fmaxf(rbx - ltx, 0.f), ih = fmaxf(rby - lty, 0.f);
                    float inter = iw * ih;
                    float iou = inter / fmaxf(ai + aj - inter, 1e-9f);
                    if (iou > 0.6f) {
                        rowW[tid * 32 + (j >> 5)] |= 1u << (j & 31);
                        nz = true;
                    }
                }
            }
        }
        zbyte[i] = nz ? 1 : 0;
    }
    __syncthreads();
    // coalesced copy of block rows to global mask
    for (int z = tid; z < ROWS_PB * 32; z += 256)
        maskG[blockIdx.x * ROWS_PB * 32 + z] = rowW[z];
}

// ---------------- K4: stage + sparse greedy scan + output (1 block x 256)
__global__ void __launch_bounds__(256) scan_out_kernel(
    const uint32_t* __restrict__ maskG, const unsigned char* __restrict__ zbyte,
    const float* __restrict__ tvalG, const int* __restrict__ tidxG,
    const float4* __restrict__ bbox, float* __restrict__ out)
{
    __shared__ uint32_t smaskL[TOPK * 32];   // 128000 B
    __shared__ uint32_t skeep32[32], validw32[32], zmaskL[32];
    int tid = threadIdx.x;
    int lane64 = tid & 63, wv = tid >> 6;
    #pragma unroll
    for (int it = 0; it < 4; ++it) {
        int j = it * 256 + tid;
        float tvj = (j < TOPK) ? tvalG[j] : -1.0f;
        u64 bal = __ballot(j < TOPK && tvj >= 0.05f);
        u64 zb  = __ballot(j < TOPK && zbyte[j] != 0);
        int w64 = it * 4 + wv;
        if (lane64 == 0) {
            validw32[w64 * 2]     = (uint32_t)bal;
            validw32[w64 * 2 + 1] = (uint32_t)(bal >> 32);
            zmaskL[w64 * 2]       = (uint32_t)zb;
            zmaskL[w64 * 2 + 1]   = (uint32_t)(zb >> 32);
        }
    }
    // unconditional coalesced stage of the full mask (pipelined, independent loads)
    for (int z = tid; z < TOPK * 32; z += 256) smaskL[z] = maskG[z];
    __syncthreads();
    // sparse greedy scan (single wave) — r14-proven
    if (tid < 32) {
        const int ln = tid;
        uint32_t vwreg = validw32[ln];
        uint32_t zreg  = zmaskL[ln];
        uint32_t sup = 0;
        for (int wc = 0; wc < 32; ++wc) {
            uint32_t nzw = (uint32_t)__builtin_amdgcn_readlane((int)zreg, wc);
            uint32_t avail = (uint32_t)__builtin_amdgcn_readlane((int)vwreg, wc)
                           & ~(uint32_t)__builtin_amdgcn_readlane((int)sup, wc);
            int p0 = -1, p1 = -1, p2 = -1;
            uint32_t R0 = 0, R1 = 0, R2 = 0;
            if (nzw) { p0 = __ffs(nzw) - 1; nzw &= nzw - 1;
                       R0 = smaskL[(wc * 32 + p0) * 32 + ln]; }
            if (nzw) { p1 = __ffs(nzw) - 1; nzw &= nzw - 1;
                       R1 = smaskL[(wc * 32 + p1) * 32 + ln]; }
            if (nzw) { p2 = __ffs(nzw) - 1; nzw &= nzw - 1;
                       R2 = smaskL[(wc * 32 + p2) * 32 + ln]; }
            while (p0 >= 0) {
                uint32_t rc = (uint32_t)__builtin_amdgcn_readlane((int)R0, wc);
                uint32_t kp = (avail >> p0) & 1u;
                uint32_t mm = 0u - kp;
                sup   |= R0 & mm;
                avail &= ~(rc & mm);
                p0 = p1; R0 = R1; p1 = p2; R1 = R2;
                if (nzw) { p2 = __ffs(nzw) - 1; nzw &= nzw - 1;
                           R2 = smaskL[(wc * 32 + p2) * 32 + ln]; }
                else p2 = -1;
            }
            if (ln == 0) skeep32[wc] = avail;   // frozen == final keep bits
        }
    }
    __syncthreads();
    // clip + output
    #pragma unroll
    for (int it = 0; it < 4; ++it) {
        int j = it * 256 + tid;
        if (j < TOPK) {
            int idx = tidxG[j];
            int p = idx / NCLS;
            int lab = idx - p * NCLS;
            float4 b = bbox[p];
            float tv = tvalG[j];
            bool kp = (skeep32[j >> 5] >> (j & 31)) & 1u;
            float x1 = fminf(fmaxf(b.x, 0.f), 224.f);
            float y1 = fminf(fmaxf(b.y, 0.f), 398.f);
            float x2 = fminf(fmaxf(b.z, 0.f), 224.f);
            float y2 = fminf(fmaxf(b.w, 0.f), 398.f);
            kp = kp && ((x2 - x1) >= 1e-5f) && ((y2 - y1) >= 1e-5f);
            out[j * 4 + 0] = kp ? x1 : 0.f;
            out[j * 4 + 1] = kp ? y1 : 0.f;
            out[j * 4 + 2] = kp ? x2 : 0.f;
            out[j * 4 + 3] = kp ? y2 : 0.f;
            out[4 * TOPK + j] = kp ? tv : -1.0f;
            out[5 * TOPK + j] = (float)lab;
            out[6 * TOPK + j] = kp ? 1.0f : 0.0f;
        }
    }
}

extern "C" void kernel_launch(void* const* d_in, const int* in_sizes, int n_in,
                              void* d_out, int out_size, void* d_ws, size_t ws_size,
                              hipStream_t stream)
{
    const float* s0 = (const float*)d_in[0];
    const float* l0 = (const float*)d_in[1];
    const float* c0 = (const float*)d_in[2];
    const float* s1 = (const float*)d_in[3];
    const float* l1 = (const float*)d_in[4];
    const float* c1 = (const float*)d_in[5];
    const float* s2 = (const float*)d_in[6];
    const float* l2 = (const float*)d_in[7];
    const float* c2 = (const float*)d_in[8];

    uint8_t* ws = (uint8_t*)d_ws;
    u64*    keys = (u64*)   (ws);              // 37520*8  = 300160 B
    float4* bbox = (float4*)(ws + 300160);     // 469*16   =   7504 B
    unsigned short* bin16 = (unsigned short*)(ws + 307664);  // 75040 B
    float*  tvalG = (float*)(ws + 382704);     // 4000 B
    int*    tidxG = (int*)  (ws + 386704);     // 4000 B
    uint32_t* maskG = (uint32_t*)(ws + 390704);// 128000 B
    unsigned char* zbyte = (unsigned char*)(ws + 518704);    // 1000 B -> 519704 total

    decode_kernel<<<dim3((NFLAT + 255) / 256), 256, 0, stream>>>(
        s0, l0, c0, s1, l1, c1, s2, l2, c2, keys, bbox, bin16);
    topk_kernel<<<1, 1024, 0, stream>>>(keys, bin16, tvalG, tidxG);
    maskbuild_kernel<<<dim3(4), 256, 0, stream>>>(tidxG, bbox, maskG, zbyte);
    scan_out_kernel<<<1, 256, 0, stream>>>(maskG, zbyte, tvalG, tidxG, bbox, (float*)d_out);
}